// Round 1
// baseline (377.848 us; speedup 1.0000x reference)
//
#include <hip/hip_runtime.h>
#include <hip/hip_bf16.h>

typedef unsigned short ushort_t;
typedef __attribute__((ext_vector_type(8))) short short8;
typedef __attribute__((ext_vector_type(8))) unsigned short ushort8;
typedef __attribute__((ext_vector_type(4))) float f32x4;

#define MFMA16(a, b, c) __builtin_amdgcn_mfma_f32_16x16x32_bf16((a), (b), (c), 0, 0, 0)

__device__ __forceinline__ ushort_t f2bf(float f) {
  unsigned int u = __builtin_bit_cast(unsigned int, f);
  u += 0x7FFFu + ((u >> 16) & 1u);   // round-to-nearest-even
  return (ushort_t)(u >> 16);
}

#define DMdim 1024
#define DPdim 128
#define PPdim 256

// workspace layout (ushort element offsets)
#define WQ_ROWS 144                    // 128 Wq rows + gate_w row + 15 zero rows
#define WQ_EXT_OFF 0
#define WO_OFF (WQ_ROWS * DMdim)                 // 147456
#define KB_OFF (WO_OFF + DMdim * DPdim)          // 278528
#define VT_OFF (KB_OFF + PPdim * DPdim)          // 311296
// total = 344064 ushort = 688128 bytes

// ---------------------------------------------------------------------------
// Prep: bf16 weight casts, k = prim@Wk^T, v^T = (prim@Wv^T)^T
// ---------------------------------------------------------------------------
__global__ void prep_kernel(const float* __restrict__ Wq, const float* __restrict__ Wk,
                            const float* __restrict__ Wv, const float* __restrict__ Wo,
                            const float* __restrict__ gate_w, const float* __restrict__ prim,
                            ushort_t* __restrict__ ws) {
  int idx = blockIdx.x * 256 + threadIdx.x;
  if (idx < WQ_ROWS * DMdim) {
    int r = idx >> 10, m = idx & (DMdim - 1);
    float v = (r < DPdim) ? Wq[r * DMdim + m] : (r == DPdim ? gate_w[m] : 0.f);
    ws[WQ_EXT_OFF + idx] = f2bf(v);
    return;
  }
  idx -= WQ_ROWS * DMdim;
  if (idx < DMdim * DPdim) { ws[WO_OFF + idx] = f2bf(Wo[idx]); return; }
  idx -= DMdim * DPdim;
  if (idx < PPdim * DPdim) {
    int p = idx >> 7, d = idx & (DPdim - 1);
    float s = 0.f;
    for (int j = 0; j < DPdim; ++j) s += prim[p * DPdim + j] * Wk[d * DPdim + j];
    ws[KB_OFF + idx] = f2bf(s);           // k[p][d], d-major (k-contig for MFMA)
    return;
  }
  idx -= PPdim * DPdim;
  if (idx < PPdim * DPdim) {
    int p = idx >> 7, d = idx & (DPdim - 1);
    float s = 0.f;
    for (int j = 0; j < DPdim; ++j) s += prim[p * DPdim + j] * Wv[d * DPdim + j];
    ws[VT_OFF + d * PPdim + p] = f2bf(s); // v^T[d][p], p-major (k-contig for PV)
  }
}

// ---------------------------------------------------------------------------
// Fused: q = x@Wq^T (+gate logit), softmax(q k^T / sqrt(dp)), ctx = attn v,
//        out = gate * (ctx @ Wo^T).  64 tokens / block, 4 waves, 16 tok/wave.
// ---------------------------------------------------------------------------
#define LDX 72    // xs row stride   (64  + 8 pad), bf16
#define LDQ 136   // q row stride    (128 + 8 pad)
#define LDA 264   // attn row stride (256 + 8 pad)
#define LDC 136   // ctx row stride

__global__ __launch_bounds__(256, 2) void fused_kernel(
    const float* __restrict__ x, const float* __restrict__ gate_b,
    const ushort_t* __restrict__ ws, float* __restrict__ out)
{
  __shared__ __align__(16) ushort_t smem[64 * LDA];   // 33,792 B (union buffer)
  __shared__ float gate_lds[64];

  const ushort_t* wq_ext = ws + WQ_EXT_OFF;
  const ushort_t* wo_b   = ws + WO_OFF;
  const ushort_t* k_b    = ws + KB_OFF;
  const ushort_t* v_t    = ws + VT_OFF;

  const int tid  = threadIdx.x;
  const int wid  = tid >> 6;
  const int lane = tid & 63;
  const int quad = lane >> 4;
  const int l16  = lane & 15;
  const int tok0 = blockIdx.x * 64;

  // ---------------- Stage A: q_ext[64][144] = x_tile @ wq_ext^T -------------
  f32x4 qacc[9];
  #pragma unroll
  for (int ct = 0; ct < 9; ++ct) qacc[ct] = (f32x4){0.f, 0.f, 0.f, 0.f};

  const int srow = tid >> 2, sseg = tid & 3;   // 64 rows x 4 segs of 16 floats

  for (int kc = 0; kc < DMdim; kc += 64) {
    const float4* xv = reinterpret_cast<const float4*>(
        x + (tok0 + srow) * DMdim + kc + sseg * 16);
    float4 f0 = xv[0], f1 = xv[1], f2 = xv[2], f3 = xv[3];
    ushort8 u0, u1;
    u0[0]=f2bf(f0.x); u0[1]=f2bf(f0.y); u0[2]=f2bf(f0.z); u0[3]=f2bf(f0.w);
    u0[4]=f2bf(f1.x); u0[5]=f2bf(f1.y); u0[6]=f2bf(f1.z); u0[7]=f2bf(f1.w);
    u1[0]=f2bf(f2.x); u1[1]=f2bf(f2.y); u1[2]=f2bf(f2.z); u1[3]=f2bf(f2.w);
    u1[4]=f2bf(f3.x); u1[5]=f2bf(f3.y); u1[6]=f2bf(f3.z); u1[7]=f2bf(f3.w);
    *reinterpret_cast<ushort8*>(&smem[srow * LDX + sseg * 16])     = u0;
    *reinterpret_cast<ushort8*>(&smem[srow * LDX + sseg * 16 + 8]) = u1;
    __syncthreads();
    #pragma unroll
    for (int ks = 0; ks < 2; ++ks) {
      short8 a = *reinterpret_cast<const short8*>(
          &smem[(wid * 16 + l16) * LDX + ks * 32 + quad * 8]);
      #pragma unroll
      for (int ct = 0; ct < 9; ++ct) {
        short8 b = *reinterpret_cast<const short8*>(
            &wq_ext[(ct * 16 + l16) * DMdim + kc + ks * 32 + quad * 8]);
        qacc[ct] = MFMA16(a, b, qacc[ct]);
      }
    }
    __syncthreads();
  }

  // q (C-layout) -> LDS [tok][128] bf16 (A-layout source); gate from ct=8,col 0
  #pragma unroll
  for (int ct = 0; ct < 8; ++ct)
    #pragma unroll
    for (int r = 0; r < 4; ++r)
      smem[(wid * 16 + quad * 4 + r) * LDQ + ct * 16 + l16] = f2bf(qacc[ct][r]);
  if (l16 == 0) {
    float gb = gate_b[0];
    #pragma unroll
    for (int r = 0; r < 4; ++r) {
      float lg = qacc[8][r] + gb;
      gate_lds[wid * 16 + quad * 4 + r] = 1.f / (1.f + __expf(-lg));
    }
  }
  __syncthreads();

  // ---------------- Stage B: scores[16][256] per wave, softmax --------------
  short8 qa[4];
  #pragma unroll
  for (int k4 = 0; k4 < 4; ++k4)
    qa[k4] = *reinterpret_cast<const short8*>(
        &smem[(wid * 16 + l16) * LDQ + k4 * 32 + quad * 8]);

  f32x4 sacc[16];
  #pragma unroll
  for (int ct = 0; ct < 16; ++ct) sacc[ct] = (f32x4){0.f, 0.f, 0.f, 0.f};
  #pragma unroll
  for (int ct = 0; ct < 16; ++ct)
    #pragma unroll
    for (int k4 = 0; k4 < 4; ++k4) {
      short8 b = *reinterpret_cast<const short8*>(
          &k_b[(ct * 16 + l16) * DPdim + k4 * 32 + quad * 8]);
      sacc[ct] = MFMA16(qa[k4], b, sacc[ct]);
    }

  const float SC = 0.08838834764831845f * 1.44269504088896f; // 1/sqrt(128)*log2e
  float rmax[4], rsum[4], inv[4];
  #pragma unroll
  for (int r = 0; r < 4; ++r) rmax[r] = -3.0e38f;
  #pragma unroll
  for (int ct = 0; ct < 16; ++ct)
    #pragma unroll
    for (int r = 0; r < 4; ++r) rmax[r] = fmaxf(rmax[r], sacc[ct][r]);
  #pragma unroll
  for (int m = 1; m < 16; m <<= 1)
    #pragma unroll
    for (int r = 0; r < 4; ++r) rmax[r] = fmaxf(rmax[r], __shfl_xor(rmax[r], m, 64));
  #pragma unroll
  for (int r = 0; r < 4; ++r) rsum[r] = 0.f;
  #pragma unroll
  for (int ct = 0; ct < 16; ++ct)
    #pragma unroll
    for (int r = 0; r < 4; ++r) {
      float e = exp2f((sacc[ct][r] - rmax[r]) * SC);
      sacc[ct][r] = e;
      rsum[r] += e;
    }
  #pragma unroll
  for (int m = 1; m < 16; m <<= 1)
    #pragma unroll
    for (int r = 0; r < 4; ++r) rsum[r] += __shfl_xor(rsum[r], m, 64);
  #pragma unroll
  for (int r = 0; r < 4; ++r) inv[r] = 1.f / rsum[r];

  __syncthreads();   // all q_lds reads done before overwrite with attn
  #pragma unroll
  for (int ct = 0; ct < 16; ++ct)
    #pragma unroll
    for (int r = 0; r < 4; ++r)
      smem[(wid * 16 + quad * 4 + r) * LDA + ct * 16 + l16] = f2bf(sacc[ct][r]);
  __syncthreads();

  // ---------------- Stage PV: ctx[16][128] = attn @ v -----------------------
  short8 pa[8];
  #pragma unroll
  for (int k8 = 0; k8 < 8; ++k8)
    pa[k8] = *reinterpret_cast<const short8*>(
        &smem[(wid * 16 + l16) * LDA + k8 * 32 + quad * 8]);
  f32x4 cacc[8];
  #pragma unroll
  for (int ct = 0; ct < 8; ++ct) cacc[ct] = (f32x4){0.f, 0.f, 0.f, 0.f};
  #pragma unroll
  for (int ct = 0; ct < 8; ++ct)
    #pragma unroll
    for (int k8 = 0; k8 < 8; ++k8) {
      short8 b = *reinterpret_cast<const short8*>(
          &v_t[(ct * 16 + l16) * PPdim + k8 * 32 + quad * 8]);
      cacc[ct] = MFMA16(pa[k8], b, cacc[ct]);
    }
  __syncthreads();   // attn reads done before overwrite with ctx
  #pragma unroll
  for (int ct = 0; ct < 8; ++ct)
    #pragma unroll
    for (int r = 0; r < 4; ++r)
      smem[(wid * 16 + quad * 4 + r) * LDC + ct * 16 + l16] =
          f2bf(cacc[ct][r] * inv[r]);   // apply 1/rowsum here
  __syncthreads();

  // ---------------- Stage C: out[64][1024] = gate * (ctx @ Wo^T) ------------
  short8 ca[4];
  #pragma unroll
  for (int k4 = 0; k4 < 4; ++k4)
    ca[k4] = *reinterpret_cast<const short8*>(
        &smem[(wid * 16 + l16) * LDC + k4 * 32 + quad * 8]);
  float g[4];
  #pragma unroll
  for (int r = 0; r < 4; ++r) g[r] = gate_lds[wid * 16 + quad * 4 + r];

  for (int mc = 0; mc < DMdim; mc += 128) {
    f32x4 oacc[8];
    #pragma unroll
    for (int ct = 0; ct < 8; ++ct) oacc[ct] = (f32x4){0.f, 0.f, 0.f, 0.f};
    #pragma unroll
    for (int ct = 0; ct < 8; ++ct)
      #pragma unroll
      for (int k4 = 0; k4 < 4; ++k4) {
        short8 b = *reinterpret_cast<const short8*>(
            &wo_b[(mc + ct * 16 + l16) * DPdim + k4 * 32 + quad * 8]);
        oacc[ct] = MFMA16(ca[k4], b, oacc[ct]);
      }
    #pragma unroll
    for (int ct = 0; ct < 8; ++ct)
      #pragma unroll
      for (int r = 0; r < 4; ++r)
        out[(tok0 + wid * 16 + quad * 4 + r) * DMdim + mc + ct * 16 + l16] =
            oacc[ct][r] * g[r];
  }
}

// ---------------------------------------------------------------------------
extern "C" void kernel_launch(void* const* d_in, const int* in_sizes, int n_in,
                              void* d_out, int out_size, void* d_ws, size_t ws_size,
                              hipStream_t stream) {
  const float* x    = (const float*)d_in[0];
  const float* prim = (const float*)d_in[1];
  const float* Wq   = (const float*)d_in[2];
  const float* Wk   = (const float*)d_in[3];
  const float* Wv   = (const float*)d_in[4];
  const float* Wo   = (const float*)d_in[5];
  const float* gw   = (const float*)d_in[6];
  const float* gb   = (const float*)d_in[7];
  float* out = (float*)d_out;
  ushort_t* ws = (ushort_t*)d_ws;

  // prep: 147456 + 131072 + 32768 + 32768 = 344064 work items
  prep_kernel<<<344064 / 256, 256, 0, stream>>>(Wq, Wk, Wv, Wo, gw, prim, ws);
  // fused: 32768 tokens / 64 per block
  fused_kernel<<<512, 256, 0, stream>>>(x, gb, ws, out);
}